// Round 1
// baseline (537.258 us; speedup 1.0000x reference)
//
#include <hip/hip_runtime.h>

#define BATCH 32
#define NUM_HEADS 32
#define HEAD_DIM 128
#define NUM_KV_HEADS 8
#define LVDIM 128
#define KV_LEN 2048
#define NUM_SPLITS 8
#define CHUNK 256           // KV_LEN / NUM_SPLITS
#define GQ 4                // NUM_HEADS / NUM_KV_HEADS
#define SM_SCALE 0.08838834764831845f  // 1/sqrt(128)

// launch_bounds(256, 8): cap VGPR at 64 so all 8 resident blocks/CU fit
// (VGPR was 60 under (256,4); LDS diet below is the real occupancy lever)
__global__ __launch_bounds__(256, 8) void decode_split_kv(
    const float* __restrict__ q,
    const float* __restrict__ k_buffer,
    const float* __restrict__ v_buffer,
    const int* __restrict__ kv_indices,
    float* __restrict__ att_out,
    float* __restrict__ att_lse)
{
    const int split = blockIdx.x;
    const int hkv   = blockIdx.y;
    const int b     = blockIdx.z;
    const int t     = threadIdx.x;

    __shared__ int s_idx[CHUNK];
    __shared__ __align__(16) float s_p[CHUNK][4];     // scores, then p=exp(s-m)
    __shared__ __align__(16) float s_po[4][GQ * 128]; // per-WAVE partial o (wave pre-reduced)
    __shared__ __align__(16) float s_red_m[4][4];
    __shared__ __align__(16) float s_red_d[4][4];

    // stage this block's 256 token indices (coalesced)
    s_idx[t] = kv_indices[b * KV_LEN + split * CHUNK + t];

    // ---- q fragments in registers (16-lane groups; scale folded in) ----
    const int lane16 = t & 15;
    const int grp16  = t >> 4;      // 0..15
    const float* qb = q + ((size_t)b * NUM_HEADS + (size_t)hkv * GQ) * HEAD_DIM;
    float4 qa[GQ], qc[GQ];
#pragma unroll
    for (int g = 0; g < GQ; ++g) {
        float4 x = *(const float4*)(qb + g * HEAD_DIM + lane16 * 4);
        float4 y = *(const float4*)(qb + g * HEAD_DIM + 64 + lane16 * 4);
        qa[g] = make_float4(x.x * SM_SCALE, x.y * SM_SCALE, x.z * SM_SCALE, x.w * SM_SCALE);
        qc[g] = make_float4(y.x * SM_SCALE, y.y * SM_SCALE, y.z * SM_SCALE, y.w * SM_SCALE);
    }
    __syncthreads();

    // ---- Phase 1: scores s[tok][g] ----
    // 16 lanes per token; lane reads 2x float4 (coalesced 256B segments)
    const float* kbase = k_buffer + (size_t)hkv * HEAD_DIM + lane16 * 4;
    for (int it = 0; it < 16; it += 4) {
        float4 ka[4], kc[4];
        const int tok0 = grp16 * 16 + it;
#pragma unroll
        for (int j = 0; j < 4; ++j) {
            const float* kp = kbase + (size_t)s_idx[tok0 + j] * (NUM_KV_HEADS * HEAD_DIM);
            ka[j] = *(const float4*)(kp);
            kc[j] = *(const float4*)(kp + 64);
        }
#pragma unroll
        for (int j = 0; j < 4; ++j) {
            float sc0 = qa[0].x * ka[j].x + qa[0].y * ka[j].y + qa[0].z * ka[j].z + qa[0].w * ka[j].w
                      + qc[0].x * kc[j].x + qc[0].y * kc[j].y + qc[0].z * kc[j].z + qc[0].w * kc[j].w;
            float sc1 = qa[1].x * ka[j].x + qa[1].y * ka[j].y + qa[1].z * ka[j].z + qa[1].w * ka[j].w
                      + qc[1].x * kc[j].x + qc[1].y * kc[j].y + qc[1].z * kc[j].z + qc[1].w * kc[j].w;
            float sc2 = qa[2].x * ka[j].x + qa[2].y * ka[j].y + qa[2].z * ka[j].z + qa[2].w * ka[j].w
                      + qc[2].x * kc[j].x + qc[2].y * kc[j].y + qc[2].z * kc[j].z + qc[2].w * kc[j].w;
            float sc3 = qa[3].x * ka[j].x + qa[3].y * ka[j].y + qa[3].z * ka[j].z + qa[3].w * ka[j].w
                      + qc[3].x * kc[j].x + qc[3].y * kc[j].y + qc[3].z * kc[j].z + qc[3].w * kc[j].w;
#pragma unroll
            for (int m = 8; m >= 1; m >>= 1) {
                sc0 += __shfl_xor(sc0, m);
                sc1 += __shfl_xor(sc1, m);
                sc2 += __shfl_xor(sc2, m);
                sc3 += __shfl_xor(sc3, m);
            }
            if (lane16 == 0) {
                *(float4*)(&s_p[tok0 + j][0]) = make_float4(sc0, sc1, sc2, sc3);
            }
        }
    }
    __syncthreads();

    // ---- softmax over the chunk (per head) ----
    float4 sv = *(const float4*)(&s_p[t][0]);   // thread t owns token t's 4 scores
    float4 mx = sv;
#pragma unroll
    for (int m = 1; m < 64; m <<= 1) {
        mx.x = fmaxf(mx.x, __shfl_xor(mx.x, m));
        mx.y = fmaxf(mx.y, __shfl_xor(mx.y, m));
        mx.z = fmaxf(mx.z, __shfl_xor(mx.z, m));
        mx.w = fmaxf(mx.w, __shfl_xor(mx.w, m));
    }
    const int wave = t >> 6;
    if ((t & 63) == 0) *(float4*)(&s_red_m[wave][0]) = mx;
    __syncthreads();
    float4 r0 = *(const float4*)(&s_red_m[0][0]);
    float4 r1 = *(const float4*)(&s_red_m[1][0]);
    float4 r2 = *(const float4*)(&s_red_m[2][0]);
    float4 r3 = *(const float4*)(&s_red_m[3][0]);
    const float m0 = fmaxf(fmaxf(r0.x, r1.x), fmaxf(r2.x, r3.x));
    const float m1 = fmaxf(fmaxf(r0.y, r1.y), fmaxf(r2.y, r3.y));
    const float m2 = fmaxf(fmaxf(r0.z, r1.z), fmaxf(r2.z, r3.z));
    const float m3 = fmaxf(fmaxf(r0.w, r1.w), fmaxf(r2.w, r3.w));

    float4 pv;
    pv.x = __expf(sv.x - m0);
    pv.y = __expf(sv.y - m1);
    pv.z = __expf(sv.z - m2);
    pv.w = __expf(sv.w - m3);
    *(float4*)(&s_p[t][0]) = pv;

    float4 sm = pv;
#pragma unroll
    for (int m = 1; m < 64; m <<= 1) {
        sm.x += __shfl_xor(sm.x, m);
        sm.y += __shfl_xor(sm.y, m);
        sm.z += __shfl_xor(sm.z, m);
        sm.w += __shfl_xor(sm.w, m);
    }
    if ((t & 63) == 0) *(float4*)(&s_red_d[wave][0]) = sm;
    __syncthreads();
    r0 = *(const float4*)(&s_red_d[0][0]);
    r1 = *(const float4*)(&s_red_d[1][0]);
    r2 = *(const float4*)(&s_red_d[2][0]);
    r3 = *(const float4*)(&s_red_d[3][0]);
    const float d0 = r0.x + r1.x + r2.x + r3.x;
    const float d1 = r0.y + r1.y + r2.y + r3.y;
    const float d2 = r0.z + r1.z + r2.z + r3.z;
    const float d3 = r0.w + r1.w + r2.w + r3.w;
    const float id0 = 1.0f / d0, id1 = 1.0f / d1, id2 = 1.0f / d2, id3 = 1.0f / d3;

    if (t == 0) {
        float* lse = att_lse + ((size_t)b * NUM_HEADS + (size_t)hkv * GQ) * NUM_SPLITS + split;
        lse[0 * NUM_SPLITS] = m0 + __logf(d0);
        lse[1 * NUM_SPLITS] = m1 + __logf(d1);
        lse[2 * NUM_SPLITS] = m2 + __logf(d2);
        lse[3 * NUM_SPLITS] = m3 + __logf(d3);
    }

    // ---- Phase 2: o[g][:] = sum_c p[g][c] * V[c][:] ----
    // 32 lanes per token row (coalesced 512B); per-lane accumulators
    const int lane32 = t & 31;
    const int grp32  = t >> 5;      // 0..7
    float4 o0 = make_float4(0.f, 0.f, 0.f, 0.f);
    float4 o1 = o0, o2 = o0, o3 = o0;
    const float* vbase = v_buffer + (size_t)hkv * LVDIM + lane32 * 4;
    for (int it = 0; it < 32; it += 4) {
        float4 vv[4], pp[4];
        const int tok0 = grp32 * 32 + it;
#pragma unroll
        for (int j = 0; j < 4; ++j) {
            vv[j] = *(const float4*)(vbase + (size_t)s_idx[tok0 + j] * (NUM_KV_HEADS * LVDIM));
            pp[j] = *(const float4*)(&s_p[tok0 + j][0]);   // broadcast read
        }
#pragma unroll
        for (int j = 0; j < 4; ++j) {
            o0.x += pp[j].x * vv[j].x; o0.y += pp[j].x * vv[j].y; o0.z += pp[j].x * vv[j].z; o0.w += pp[j].x * vv[j].w;
            o1.x += pp[j].y * vv[j].x; o1.y += pp[j].y * vv[j].y; o1.z += pp[j].y * vv[j].z; o1.w += pp[j].y * vv[j].w;
            o2.x += pp[j].z * vv[j].x; o2.y += pp[j].z * vv[j].y; o2.z += pp[j].z * vv[j].z; o2.w += pp[j].z * vv[j].w;
            o3.x += pp[j].w * vv[j].x; o3.y += pp[j].w * vv[j].y; o3.z += pp[j].w * vv[j].z; o3.w += pp[j].w * vv[j].w;
        }
    }

    // ---- wave-level pre-reduce: combine the two 32-lane groups of each wave
    // lane l and l+32 hold the same V columns for disjoint token halves
    o0.x += __shfl_xor(o0.x, 32); o0.y += __shfl_xor(o0.y, 32); o0.z += __shfl_xor(o0.z, 32); o0.w += __shfl_xor(o0.w, 32);
    o1.x += __shfl_xor(o1.x, 32); o1.y += __shfl_xor(o1.y, 32); o1.z += __shfl_xor(o1.z, 32); o1.w += __shfl_xor(o1.w, 32);
    o2.x += __shfl_xor(o2.x, 32); o2.y += __shfl_xor(o2.y, 32); o2.z += __shfl_xor(o2.z, 32); o2.w += __shfl_xor(o2.w, 32);
    o3.x += __shfl_xor(o3.x, 32); o3.y += __shfl_xor(o3.y, 32); o3.z += __shfl_xor(o3.z, 32); o3.w += __shfl_xor(o3.w, 32);

    if ((t & 32) == 0) {
        float* po = &s_po[wave][0];
        *(float4*)(po + 0 * 128 + lane32 * 4) = o0;
        *(float4*)(po + 1 * 128 + lane32 * 4) = o1;
        *(float4*)(po + 2 * 128 + lane32 * 4) = o2;
        *(float4*)(po + 3 * 128 + lane32 * 4) = o3;
    }
    __syncthreads();

    // ---- final cross-wave reduce + normalize + store ----
#pragma unroll
    for (int r = 0; r < 2; ++r) {
        const int oi = t + r * 256;          // oi = g*128 + lv
        float acc = s_po[0][oi] + s_po[1][oi] + s_po[2][oi] + s_po[3][oi];
        const int g  = oi >> 7;
        const int lv = oi & 127;
        const float invd = (g & 2) ? ((g & 1) ? id3 : id2) : ((g & 1) ? id1 : id0);
        att_out[(((size_t)b * NUM_HEADS + (size_t)hkv * GQ + g) * NUM_SPLITS + split) * LVDIM + lv] = acc * invd;
    }
}

extern "C" void kernel_launch(void* const* d_in, const int* in_sizes, int n_in,
                              void* d_out, int out_size, void* d_ws, size_t ws_size,
                              hipStream_t stream) {
    const float* q         = (const float*)d_in[0];
    const float* k_buffer  = (const float*)d_in[1];
    const float* v_buffer  = (const float*)d_in[2];
    const int*   kv_indptr = (const int*)d_in[3];
    const int*   kv_indices= (const int*)d_in[4];
    (void)kv_indptr; (void)in_sizes; (void)n_in; (void)d_ws; (void)ws_size; (void)out_size;
    // d_in[5] = num_kv_splits (scalar) — fixed at 8 for this problem

    float* att_out = (float*)d_out;
    float* att_lse = att_out + (size_t)BATCH * NUM_HEADS * NUM_SPLITS * LVDIM;

    dim3 grid(NUM_SPLITS, NUM_KV_HEADS, BATCH);
    decode_split_kv<<<grid, 256, 0, stream>>>(q, k_buffer, v_buffer, kv_indices, att_out, att_lse);
}

// Round 2
// 521.878 us; speedup vs baseline: 1.0295x; 1.0295x over previous
//
#include <hip/hip_runtime.h>

#define BATCH 32
#define NUM_HEADS 32
#define HEAD_DIM 128
#define NUM_KV_HEADS 8
#define LVDIM 128
#define KV_LEN 2048
#define NUM_SPLITS 8
#define CHUNK 256           // KV_LEN / NUM_SPLITS
#define GQ 4                // NUM_HEADS / NUM_KV_HEADS
#define SM_SCALE 0.08838834764831845f  // 1/sqrt(128)

// launch_bounds(256,4): empirically cap ~64 VGPR (round-0 fit in 60, no spills).
// (256,8) forced VGPR=32 -> ~100MB scratch spill traffic per dispatch (round 1).
// LDS diet (13824B) keeps LDS non-binding: 11 blocks/CU vs 8 offered by grid.
__global__ __launch_bounds__(256, 4) void decode_split_kv(
    const float* __restrict__ q,
    const float* __restrict__ k_buffer,
    const float* __restrict__ v_buffer,
    const int* __restrict__ kv_indices,
    float* __restrict__ att_out,
    float* __restrict__ att_lse)
{
    const int split = blockIdx.x;
    const int hkv   = blockIdx.y;
    const int b     = blockIdx.z;
    const int t     = threadIdx.x;

    __shared__ int s_idx[CHUNK];
    __shared__ __align__(16) float s_p[CHUNK][4];     // scores, then p=exp(s-m)
    __shared__ __align__(16) float s_po[4][GQ * 128]; // per-WAVE partial o (wave pre-reduced)
    __shared__ __align__(16) float s_red_m[4][4];
    __shared__ __align__(16) float s_red_d[4][4];

    // stage this block's 256 token indices (coalesced)
    s_idx[t] = kv_indices[b * KV_LEN + split * CHUNK + t];

    // ---- q fragments in registers (16-lane groups; scale folded in) ----
    const int lane16 = t & 15;
    const int grp16  = t >> 4;      // 0..15
    const float* qb = q + ((size_t)b * NUM_HEADS + (size_t)hkv * GQ) * HEAD_DIM;
    float4 qa[GQ], qc[GQ];
#pragma unroll
    for (int g = 0; g < GQ; ++g) {
        float4 x = *(const float4*)(qb + g * HEAD_DIM + lane16 * 4);
        float4 y = *(const float4*)(qb + g * HEAD_DIM + 64 + lane16 * 4);
        qa[g] = make_float4(x.x * SM_SCALE, x.y * SM_SCALE, x.z * SM_SCALE, x.w * SM_SCALE);
        qc[g] = make_float4(y.x * SM_SCALE, y.y * SM_SCALE, y.z * SM_SCALE, y.w * SM_SCALE);
    }
    __syncthreads();

    // ---- Phase 1: scores s[tok][g] ----
    // 16 lanes per token; lane reads 2x float4 (coalesced 256B segments)
    const float* kbase = k_buffer + (size_t)hkv * HEAD_DIM + lane16 * 4;
    for (int it = 0; it < 16; it += 4) {
        float4 ka[4], kc[4];
        const int tok0 = grp16 * 16 + it;
#pragma unroll
        for (int j = 0; j < 4; ++j) {
            const float* kp = kbase + (size_t)s_idx[tok0 + j] * (NUM_KV_HEADS * HEAD_DIM);
            ka[j] = *(const float4*)(kp);
            kc[j] = *(const float4*)(kp + 64);
        }
#pragma unroll
        for (int j = 0; j < 4; ++j) {
            float sc0 = qa[0].x * ka[j].x + qa[0].y * ka[j].y + qa[0].z * ka[j].z + qa[0].w * ka[j].w
                      + qc[0].x * kc[j].x + qc[0].y * kc[j].y + qc[0].z * kc[j].z + qc[0].w * kc[j].w;
            float sc1 = qa[1].x * ka[j].x + qa[1].y * ka[j].y + qa[1].z * ka[j].z + qa[1].w * ka[j].w
                      + qc[1].x * kc[j].x + qc[1].y * kc[j].y + qc[1].z * kc[j].z + qc[1].w * kc[j].w;
            float sc2 = qa[2].x * ka[j].x + qa[2].y * ka[j].y + qa[2].z * ka[j].z + qa[2].w * ka[j].w
                      + qc[2].x * kc[j].x + qc[2].y * kc[j].y + qc[2].z * kc[j].z + qc[2].w * kc[j].w;
            float sc3 = qa[3].x * ka[j].x + qa[3].y * ka[j].y + qa[3].z * ka[j].z + qa[3].w * ka[j].w
                      + qc[3].x * kc[j].x + qc[3].y * kc[j].y + qc[3].z * kc[j].z + qc[3].w * kc[j].w;
#pragma unroll
            for (int m = 8; m >= 1; m >>= 1) {
                sc0 += __shfl_xor(sc0, m);
                sc1 += __shfl_xor(sc1, m);
                sc2 += __shfl_xor(sc2, m);
                sc3 += __shfl_xor(sc3, m);
            }
            if (lane16 == 0) {
                *(float4*)(&s_p[tok0 + j][0]) = make_float4(sc0, sc1, sc2, sc3);
            }
        }
    }
    __syncthreads();

    // ---- softmax over the chunk (per head) ----
    float4 sv = *(const float4*)(&s_p[t][0]);   // thread t owns token t's 4 scores
    float4 mx = sv;
#pragma unroll
    for (int m = 1; m < 64; m <<= 1) {
        mx.x = fmaxf(mx.x, __shfl_xor(mx.x, m));
        mx.y = fmaxf(mx.y, __shfl_xor(mx.y, m));
        mx.z = fmaxf(mx.z, __shfl_xor(mx.z, m));
        mx.w = fmaxf(mx.w, __shfl_xor(mx.w, m));
    }
    const int wave = t >> 6;
    if ((t & 63) == 0) *(float4*)(&s_red_m[wave][0]) = mx;
    __syncthreads();
    float4 r0 = *(const float4*)(&s_red_m[0][0]);
    float4 r1 = *(const float4*)(&s_red_m[1][0]);
    float4 r2 = *(const float4*)(&s_red_m[2][0]);
    float4 r3 = *(const float4*)(&s_red_m[3][0]);
    const float m0 = fmaxf(fmaxf(r0.x, r1.x), fmaxf(r2.x, r3.x));
    const float m1 = fmaxf(fmaxf(r0.y, r1.y), fmaxf(r2.y, r3.y));
    const float m2 = fmaxf(fmaxf(r0.z, r1.z), fmaxf(r2.z, r3.z));
    const float m3 = fmaxf(fmaxf(r0.w, r1.w), fmaxf(r2.w, r3.w));

    float4 pv;
    pv.x = __expf(sv.x - m0);
    pv.y = __expf(sv.y - m1);
    pv.z = __expf(sv.z - m2);
    pv.w = __expf(sv.w - m3);
    *(float4*)(&s_p[t][0]) = pv;

    float4 sm = pv;
#pragma unroll
    for (int m = 1; m < 64; m <<= 1) {
        sm.x += __shfl_xor(sm.x, m);
        sm.y += __shfl_xor(sm.y, m);
        sm.z += __shfl_xor(sm.z, m);
        sm.w += __shfl_xor(sm.w, m);
    }
    if ((t & 63) == 0) *(float4*)(&s_red_d[wave][0]) = sm;
    __syncthreads();
    r0 = *(const float4*)(&s_red_d[0][0]);
    r1 = *(const float4*)(&s_red_d[1][0]);
    r2 = *(const float4*)(&s_red_d[2][0]);
    r3 = *(const float4*)(&s_red_d[3][0]);
    const float d0 = r0.x + r1.x + r2.x + r3.x;
    const float d1 = r0.y + r1.y + r2.y + r3.y;
    const float d2 = r0.z + r1.z + r2.z + r3.z;
    const float d3 = r0.w + r1.w + r2.w + r3.w;
    const float id0 = 1.0f / d0, id1 = 1.0f / d1, id2 = 1.0f / d2, id3 = 1.0f / d3;

    if (t == 0) {
        float* lse = att_lse + ((size_t)b * NUM_HEADS + (size_t)hkv * GQ) * NUM_SPLITS + split;
        lse[0 * NUM_SPLITS] = m0 + __logf(d0);
        lse[1 * NUM_SPLITS] = m1 + __logf(d1);
        lse[2 * NUM_SPLITS] = m2 + __logf(d2);
        lse[3 * NUM_SPLITS] = m3 + __logf(d3);
    }

    // ---- Phase 2: o[g][:] = sum_c p[g][c] * V[c][:] ----
    // 32 lanes per token row (coalesced 512B); per-lane accumulators
    const int lane32 = t & 31;
    const int grp32  = t >> 5;      // 0..7
    float4 o0 = make_float4(0.f, 0.f, 0.f, 0.f);
    float4 o1 = o0, o2 = o0, o3 = o0;
    const float* vbase = v_buffer + (size_t)hkv * LVDIM + lane32 * 4;
    for (int it = 0; it < 32; it += 4) {
        float4 vv[4], pp[4];
        const int tok0 = grp32 * 32 + it;
#pragma unroll
        for (int j = 0; j < 4; ++j) {
            vv[j] = *(const float4*)(vbase + (size_t)s_idx[tok0 + j] * (NUM_KV_HEADS * LVDIM));
            pp[j] = *(const float4*)(&s_p[tok0 + j][0]);   // broadcast read
        }
#pragma unroll
        for (int j = 0; j < 4; ++j) {
            o0.x += pp[j].x * vv[j].x; o0.y += pp[j].x * vv[j].y; o0.z += pp[j].x * vv[j].z; o0.w += pp[j].x * vv[j].w;
            o1.x += pp[j].y * vv[j].x; o1.y += pp[j].y * vv[j].y; o1.z += pp[j].y * vv[j].z; o1.w += pp[j].y * vv[j].w;
            o2.x += pp[j].z * vv[j].x; o2.y += pp[j].z * vv[j].y; o2.z += pp[j].z * vv[j].z; o2.w += pp[j].z * vv[j].w;
            o3.x += pp[j].w * vv[j].x; o3.y += pp[j].w * vv[j].y; o3.z += pp[j].w * vv[j].z; o3.w += pp[j].w * vv[j].w;
        }
    }

    // ---- wave-level pre-reduce: combine the two 32-lane groups of each wave
    // lane l and l+32 hold the same V columns for disjoint token halves
    o0.x += __shfl_xor(o0.x, 32); o0.y += __shfl_xor(o0.y, 32); o0.z += __shfl_xor(o0.z, 32); o0.w += __shfl_xor(o0.w, 32);
    o1.x += __shfl_xor(o1.x, 32); o1.y += __shfl_xor(o1.y, 32); o1.z += __shfl_xor(o1.z, 32); o1.w += __shfl_xor(o1.w, 32);
    o2.x += __shfl_xor(o2.x, 32); o2.y += __shfl_xor(o2.y, 32); o2.z += __shfl_xor(o2.z, 32); o2.w += __shfl_xor(o2.w, 32);
    o3.x += __shfl_xor(o3.x, 32); o3.y += __shfl_xor(o3.y, 32); o3.z += __shfl_xor(o3.z, 32); o3.w += __shfl_xor(o3.w, 32);

    if ((t & 32) == 0) {
        float* po = &s_po[wave][0];
        *(float4*)(po + 0 * 128 + lane32 * 4) = o0;
        *(float4*)(po + 1 * 128 + lane32 * 4) = o1;
        *(float4*)(po + 2 * 128 + lane32 * 4) = o2;
        *(float4*)(po + 3 * 128 + lane32 * 4) = o3;
    }
    __syncthreads();

    // ---- final cross-wave reduce + normalize + store ----
#pragma unroll
    for (int r = 0; r < 2; ++r) {
        const int oi = t + r * 256;          // oi = g*128 + lv
        float acc = s_po[0][oi] + s_po[1][oi] + s_po[2][oi] + s_po[3][oi];
        const int g  = oi >> 7;
        const int lv = oi & 127;
        const float invd = (g & 2) ? ((g & 1) ? id3 : id2) : ((g & 1) ? id1 : id0);
        att_out[(((size_t)b * NUM_HEADS + (size_t)hkv * GQ + g) * NUM_SPLITS + split) * LVDIM + lv] = acc * invd;
    }
}

extern "C" void kernel_launch(void* const* d_in, const int* in_sizes, int n_in,
                              void* d_out, int out_size, void* d_ws, size_t ws_size,
                              hipStream_t stream) {
    const float* q         = (const float*)d_in[0];
    const float* k_buffer  = (const float*)d_in[1];
    const float* v_buffer  = (const float*)d_in[2];
    const int*   kv_indptr = (const int*)d_in[3];
    const int*   kv_indices= (const int*)d_in[4];
    (void)kv_indptr; (void)in_sizes; (void)n_in; (void)d_ws; (void)ws_size; (void)out_size;
    // d_in[5] = num_kv_splits (scalar) — fixed at 8 for this problem

    float* att_out = (float*)d_out;
    float* att_lse = att_out + (size_t)BATCH * NUM_HEADS * NUM_SPLITS * LVDIM;

    dim3 grid(NUM_SPLITS, NUM_KV_HEADS, BATCH);
    decode_split_kv<<<grid, 256, 0, stream>>>(q, k_buffer, v_buffer, kv_indices, att_out, att_lse);
}